// Round 2
// baseline (70.784 us; speedup 1.0000x reference)
//
#include <hip/hip_runtime.h>
#include <hip/hip_bf16.h>

#define BB 16
#define TT 2048
#define HH 1024
#define NTAGS 74
#define NPAD 80

typedef __bf16 bf16x8 __attribute__((ext_vector_type(8)));
typedef float f32x4 __attribute__((ext_vector_type(4)));

// Transpose + convert W_out [1024][74] f32 -> Wt [80][1024] bf16 (pad cols 74..79 = 0)
__global__ __launch_bounds__(256) void prep_w_kernel(const float* __restrict__ W,
                                                     __bf16* __restrict__ Wt) {
    __shared__ float tile[64][80];
    const int k0 = blockIdx.x * 64;
    const int tid = threadIdx.x;
    for (int i = tid; i < 64 * NTAGS; i += 256) {
        int k = i / NTAGS, n = i - k * NTAGS;
        tile[k][n] = W[(k0 + k) * NTAGS + n];
    }
    __syncthreads();
    for (int i = tid; i < NPAD * 64; i += 256) {
        int n = i >> 6, kk = i & 63;
        float v = (n < NTAGS) ? tile[kk][n] : 0.0f;
        Wt[n * HH + k0 + kk] = (__bf16)v;
    }
}

// Fused gather-blend-mask + GEMM [B*T,1024] x [1024,74] via 16x16x32 bf16 MFMA.
// Block = 256 threads = 4 waves; each wave owns 16 rows x 80 (padded) cols.
// A-fragments built straight from global (no LDS): lane l -> row (l&15),
// k = (l>>4)*8..+8 contiguous. Any k-permutation in the true fragment layout
// cancels because A and B use the identical lane->k mapping.
__global__ __launch_bounds__(256) void slu_main(const float* __restrict__ out_char,
                                                const float* __restrict__ out_word,
                                                const int* __restrict__ word_idx,
                                                const int* __restrict__ is_head,
                                                const int* __restrict__ valid_mask,
                                                const __bf16* __restrict__ Wt,
                                                const float* __restrict__ b_out,
                                                float* __restrict__ out) {
    const int tid = threadIdx.x;
    const int wv = tid >> 6;      // wave 0..3
    const int lane = tid & 63;
    const int l15 = lane & 15;
    const int kgrp = lane >> 4;   // 0..3

    const int row = blockIdx.x * 64 + wv * 16 + l15;  // this lane's A row
    const int b = row >> 11;                          // T = 2048
    const int t = row & (TT - 1);
    const int bt = b * TT + t;

    const int widx = word_idx[bt];
    const bool val = valid_mask[bt] != 0;
    const bool head = is_head[bt] != 0;
    const float rate = val ? (head ? 0.88f : 0.70f) : 0.0f;
    const float crate = val ? (1.0f - (head ? 0.88f : 0.70f)) : 0.0f;

    const float* cp = out_char + (size_t)bt * HH + kgrp * 8;
    const float* wp = out_word + ((size_t)b * TT + widx) * HH + kgrp * 8;
    const __bf16* wtp = Wt + l15 * HH + kgrp * 8;

    f32x4 acc[5];
#pragma unroll
    for (int nt = 0; nt < 5; ++nt) acc[nt] = (f32x4){0.0f, 0.0f, 0.0f, 0.0f};

    for (int k0 = 0; k0 < HH; k0 += 32) {
        bf16x8 a;
        if (val) {
            float4 ca = *(const float4*)(cp + k0);
            float4 cb = *(const float4*)(cp + k0 + 4);
            float4 wa = *(const float4*)(wp + k0);
            float4 wb = *(const float4*)(wp + k0 + 4);
            a[0] = (__bf16)(wa.x * rate + ca.x * crate);
            a[1] = (__bf16)(wa.y * rate + ca.y * crate);
            a[2] = (__bf16)(wa.z * rate + ca.z * crate);
            a[3] = (__bf16)(wa.w * rate + ca.w * crate);
            a[4] = (__bf16)(wb.x * rate + cb.x * crate);
            a[5] = (__bf16)(wb.y * rate + cb.y * crate);
            a[6] = (__bf16)(wb.z * rate + cb.z * crate);
            a[7] = (__bf16)(wb.w * rate + cb.w * crate);
        } else {
#pragma unroll
            for (int e = 0; e < 8; ++e) a[e] = (__bf16)0.0f;
        }
#pragma unroll
        for (int nt = 0; nt < 5; ++nt) {
            bf16x8 bf = *(const bf16x8*)(wtp + nt * 16 * HH + k0);
            acc[nt] = __builtin_amdgcn_mfma_f32_16x16x32_bf16(a, bf, acc[nt], 0, 0, 0);
        }
    }

    // C/D layout: col = lane&15, row = (lane>>4)*4 + reg   [m89-verified]
    const int orow = blockIdx.x * 64 + wv * 16 + kgrp * 4;
#pragma unroll
    for (int nt = 0; nt < 5; ++nt) {
        const int col = nt * 16 + l15;
        if (col < NTAGS) {
            const float bias = b_out[col];
#pragma unroll
            for (int i = 0; i < 4; ++i) {
                out[(size_t)(orow + i) * NTAGS + col] = acc[nt][i] + bias;
            }
        }
    }
}

extern "C" void kernel_launch(void* const* d_in, const int* in_sizes, int n_in,
                              void* d_out, int out_size, void* d_ws, size_t ws_size,
                              hipStream_t stream) {
    const float* out_char = (const float*)d_in[0];
    const float* out_word = (const float*)d_in[1];
    const int* word_idx = (const int*)d_in[2];
    const int* is_head = (const int*)d_in[3];
    const int* valid_mask = (const int*)d_in[4];
    const float* W_out = (const float*)d_in[5];
    const float* b_out = (const float*)d_in[6];
    float* out = (float*)d_out;
    __bf16* Wt = (__bf16*)d_ws;  // 80*1024*2 = 160 KB

    prep_w_kernel<<<HH / 64, 256, 0, stream>>>(W_out, Wt);

    const int rows = BB * TT;
    slu_main<<<rows / 64, 256, 0, stream>>>(out_char, out_word, word_idx, is_head,
                                            valid_mask, Wt, b_out, out);
}